// Round 1
// baseline (776.933 us; speedup 1.0000x reference)
//
#include <hip/hip_runtime.h>

typedef float floatx4 __attribute__((ext_vector_type(4)));
typedef _Float16 half_t;
typedef _Float16 halfx8 __attribute__((ext_vector_type(8)));
typedef _Float16 halfx4 __attribute__((ext_vector_type(4)));

#define S_LEN 2048
#define HDIM 3584
#define NHEADS 28
#define NKVH 4
#define GRP 7
#define DHEAD 128
#define KVDIM 512   // NKVH*DHEAD

// ---------------------------------------------------------------------------
// Shared GEMM tile body: C[m][n] = sum_k A[m][k] * B[n][k] (+ bias[n])
// 128x128 tile, BK=32, 4 waves, each wave 64x64 = 4x4 MFMA 16x16x32 f16.
// A is fp32 (converted inline) or f16; B always fp32 (converted inline).
// LDS stride 56 halves = 112B: rows 16B-aligned, 28-bank stride (2-way free).
// ---------------------------------------------------------------------------
template<bool A_IS_HALF, bool OUT_HALF, bool HAS_BIAS>
__device__ __forceinline__ void gemm_tile(
    const void* __restrict__ Ap, const float* __restrict__ B,
    const float* __restrict__ bias, void* __restrict__ Cp,
    long bm, long bn, int N, int K, half_t* As, half_t* Bs)
{
    constexpr int LDSS = 56;
    const int tid  = threadIdx.x;
    const int lane = tid & 63;
    const int wave = tid >> 6;
    const int wm = (wave >> 1) * 64;
    const int wn = (wave & 1) * 64;
    const int lrow = lane & 15;
    const int quad = lane >> 4;
    const int k0 = quad * 8;

    floatx4 acc[4][4] = {};

    for (int kb = 0; kb < K; kb += 32) {
        __syncthreads();
        if constexpr (A_IS_HALF) {
            const half_t* Af = (const half_t*)Ap;
            #pragma unroll
            for (int i = 0; i < 2; i++) {
                int f = tid + i * 256;        // 0..511
                int row = f >> 2;             // 0..127
                int col = (f & 3) * 8;        // 0..24
                *(halfx8*)&As[row * LDSS + col] =
                    *(const halfx8*)&Af[(bm + row) * (long)K + kb + col];
            }
        } else {
            const float* Af = (const float*)Ap;
            #pragma unroll
            for (int i = 0; i < 4; i++) {
                int f = tid + i * 256;        // 0..1023
                int row = f >> 3;             // 0..127
                int col = (f & 7) * 4;        // 0..28
                floatx4 d = *(const floatx4*)&Af[(bm + row) * (long)K + kb + col];
                halfx4 h;
                h[0] = (half_t)d[0]; h[1] = (half_t)d[1];
                h[2] = (half_t)d[2]; h[3] = (half_t)d[3];
                *(halfx4*)&As[row * LDSS + col] = h;
            }
        }
        #pragma unroll
        for (int i = 0; i < 4; i++) {
            int f = tid + i * 256;
            int row = f >> 3;
            int col = (f & 7) * 4;
            floatx4 d = *(const floatx4*)&B[(bn + row) * (long)K + kb + col];
            halfx4 h;
            h[0] = (half_t)d[0]; h[1] = (half_t)d[1];
            h[2] = (half_t)d[2]; h[3] = (half_t)d[3];
            *(halfx4*)&Bs[row * LDSS + col] = h;
        }
        __syncthreads();

        halfx8 af[4], bf[4];
        #pragma unroll
        for (int i = 0; i < 4; i++)
            af[i] = *(const halfx8*)&As[(wm + i * 16 + lrow) * LDSS + k0];
        #pragma unroll
        for (int j = 0; j < 4; j++)
            bf[j] = *(const halfx8*)&Bs[(wn + j * 16 + lrow) * LDSS + k0];
        #pragma unroll
        for (int i = 0; i < 4; i++)
            #pragma unroll
            for (int j = 0; j < 4; j++)
                acc[i][j] = __builtin_amdgcn_mfma_f32_16x16x32_f16(
                    af[i], bf[j], acc[i][j], 0, 0, 0);
    }

    // Epilogue: C/D layout col=lane&15, row=quad*4+reg
    #pragma unroll
    for (int j = 0; j < 4; j++) {
        long col = bn + wn + j * 16 + lrow;
        float bv = HAS_BIAS ? bias[col] : 0.0f;
        #pragma unroll
        for (int i = 0; i < 4; i++) {
            long rbase = bm + wm + i * 16 + quad * 4;
            #pragma unroll
            for (int r = 0; r < 4; r++) {
                float v = acc[i][j][r] + bv;
                if constexpr (OUT_HALF)
                    ((half_t*)Cp)[(rbase + r) * (long)N + col] = (half_t)v;
                else
                    ((float*)Cp)[(rbase + r) * (long)N + col] = v;
            }
        }
    }
}

// Fused QKV projection: grid (36,16); bx<28 -> Q, <32 -> K, else V.
__global__ __launch_bounds__(256) void qkv_kernel(
    const float* __restrict__ hidden,
    const float* __restrict__ Wq, const float* __restrict__ bq,
    const float* __restrict__ Wk, const float* __restrict__ bk,
    const float* __restrict__ Wv, const float* __restrict__ bv,
    half_t* __restrict__ q, half_t* __restrict__ k, half_t* __restrict__ v)
{
    __shared__ half_t As[128 * 56];
    __shared__ half_t Bs[128 * 56];
    int bx = blockIdx.x;
    const float *B, *bias; half_t* C; long bn; int N;
    if (bx < 28)      { B = Wq; bias = bq; C = q; bn = (long)bx * 128;        N = HDIM;  }
    else if (bx < 32) { B = Wk; bias = bk; C = k; bn = (long)(bx - 28) * 128; N = KVDIM; }
    else              { B = Wv; bias = bv; C = v; bn = (long)(bx - 32) * 128; N = KVDIM; }
    gemm_tile<false, true, true>(hidden, B, bias, C,
                                 (long)blockIdx.y * 128, bn, N, HDIM, As, Bs);
}

// Output projection: out = o @ Wo^T (fp32 out)
__global__ __launch_bounds__(256) void oproj_kernel(
    const half_t* __restrict__ o, const float* __restrict__ Wo,
    float* __restrict__ out)
{
    __shared__ half_t As[128 * 56];
    __shared__ half_t Bs[128 * 56];
    gemm_tile<true, false, false>(o, Wo, nullptr, out,
                                  (long)blockIdx.y * 128, (long)blockIdx.x * 128,
                                  HDIM, HDIM, As, Bs);
}

// In-place RoPE on q (with 1/sqrt(D) scale folded in) and k.
// One thread per (s, head, d<64) pair. Grid exactly covers both.
__global__ __launch_bounds__(256) void rope_kernel(
    half_t* __restrict__ q, half_t* __restrict__ k,
    const float* __restrict__ ct, const float* __restrict__ st)
{
    const float scale = 0.08838834764831845f; // 128^-0.5
    int idx = blockIdx.x * 256 + threadIdx.x;
    const int QP = S_LEN * NHEADS * 64;
    half_t* base; int s, d; float sc;
    if (idx < QP) {
        s = idx / (NHEADS * 64);
        int rem = idx % (NHEADS * 64);
        int h = rem >> 6; d = rem & 63;
        base = q + (long)s * HDIM + h * 128 + d;
        sc = scale;
    } else {
        int j = idx - QP;
        s = j / (NKVH * 64);
        int rem = j % (NKVH * 64);
        int h = rem >> 6; d = rem & 63;
        base = k + (long)s * KVDIM + h * 128 + d;
        sc = 1.0f;
    }
    float c = ct[s * 128 + d], sn = st[s * 128 + d];
    float x1 = (float)base[0], x2 = (float)base[64];
    base[0]  = (half_t)((x1 * c - x2 * sn) * sc);
    base[64] = (half_t)((x2 * c + x1 * sn) * sc);
}

// Flash attention with causal + doc-id mask. Block = (64 q rows, 1 head),
// 4 waves x 16 rows. K-chunks of 32 keys staged in LDS; P round-trips
// through per-wave LDS to convert C-layout -> A-layout (m120 pattern).
__global__ __launch_bounds__(256) void attn_kernel(
    const half_t* __restrict__ q, const half_t* __restrict__ k,
    const half_t* __restrict__ v, const int* __restrict__ doc,
    half_t* __restrict__ o)
{
    constexpr int KS = 136; // 272B rows: 16B-aligned, 4-bank stride (2-way free)
    constexpr int VS = 40;  // 80B rows
    constexpr int PS = 40;
    __shared__ half_t Ks[32 * KS];
    __shared__ half_t Vt[128 * VS];
    __shared__ half_t Ps[4][16 * PS];

    const int tid  = threadIdx.x;
    const int lane = tid & 63;
    const int wave = tid >> 6;
    const int head = blockIdx.y;
    const int kvh  = head / GRP;
    const int qbase = blockIdx.x * 64;
    const int lrow = lane & 15;
    const int quad = lane >> 4;
    const int k0 = quad * 8;

    // Q fragments for 4 K-steps (d = kk*32 + quad*8 + j), rows qbase+wave*16+lrow
    const int qrow = qbase + wave * 16 + lrow;
    halfx8 qf[4];
    #pragma unroll
    for (int kk = 0; kk < 4; kk++)
        qf[kk] = *(const halfx8*)&q[(long)qrow * HDIM + head * 128 + kk * 32 + k0];

    int qdoc[4], qpos[4];
    #pragma unroll
    for (int r = 0; r < 4; r++) {
        qpos[r] = qbase + wave * 16 + quad * 4 + r;
        qdoc[r] = doc[qpos[r]];
    }

    float m_r[4], l_r[4];
    floatx4 oacc[8] = {};
    #pragma unroll
    for (int r = 0; r < 4; r++) { m_r[r] = -INFINITY; l_r[r] = 0.0f; }

    const int nchunk = qbase / 32 + 2; // causal: kbase <= qbase+63

    for (int c = 0; c < nchunk; c++) {
        int kbase = c * 32;
        __syncthreads();
        // stage K chunk: Ks[key][d]
        #pragma unroll
        for (int i = 0; i < 2; i++) {
            int f = tid + i * 256;    // 0..511
            int key = f >> 4;         // 0..31
            int d = (f & 15) * 8;
            *(halfx8*)&Ks[key * KS + d] =
                *(const halfx8*)&k[(long)(kbase + key) * KVDIM + kvh * 128 + d];
        }
        // stage V transposed: Vt[d][key]
        #pragma unroll
        for (int i = 0; i < 16; i++) {
            int e = tid + i * 256;    // 0..4095
            int key = e >> 7;
            int d = e & 127;
            Vt[d * VS + key] = v[(long)(kbase + key) * KVDIM + kvh * 128 + d];
        }
        __syncthreads();

        // QK^T: two 16-key sub-tiles
        floatx4 sacc[2] = {};
        #pragma unroll
        for (int kk = 0; kk < 4; kk++) {
            halfx8 b0 = *(const halfx8*)&Ks[lrow * KS + kk * 32 + k0];
            halfx8 b1 = *(const halfx8*)&Ks[(16 + lrow) * KS + kk * 32 + k0];
            sacc[0] = __builtin_amdgcn_mfma_f32_16x16x32_f16(qf[kk], b0, sacc[0], 0, 0, 0);
            sacc[1] = __builtin_amdgcn_mfma_f32_16x16x32_f16(qf[kk], b1, sacc[1], 0, 0, 0);
        }

        // mask + online softmax (rows quad*4+r, col = lane&15 within sub-tile)
        int kp0 = kbase + lrow;
        int kp1 = kbase + 16 + lrow;
        int kd0 = doc[kp0];
        int kd1 = doc[kp1];
        float pk[2][4];
        float alpha[4];
        #pragma unroll
        for (int r = 0; r < 4; r++) {
            float s0 = sacc[0][r];
            float s1 = sacc[1][r];
            bool v0 = (kp0 <= qpos[r]) && (kd0 == qdoc[r]);
            bool v1 = (kp1 <= qpos[r]) && (kd1 == qdoc[r]);
            s0 = v0 ? s0 : -INFINITY;
            s1 = v1 ? s1 : -INFINITY;
            float mx = fmaxf(s0, s1);
            #pragma unroll
            for (int off = 1; off < 16; off <<= 1)
                mx = fmaxf(mx, __shfl_xor(mx, off));
            float mnew = fmaxf(m_r[r], mx);
            bool noinf = (mnew != -INFINITY);
            alpha[r] = noinf ? __expf(m_r[r] - mnew) : 1.0f;
            float p0 = noinf ? __expf(s0 - mnew) : 0.0f;
            float p1 = noinf ? __expf(s1 - mnew) : 0.0f;
            pk[0][r] = p0; pk[1][r] = p1;
            float sm = p0 + p1;
            #pragma unroll
            for (int off = 1; off < 16; off <<= 1)
                sm += __shfl_xor(sm, off);
            l_r[r] = l_r[r] * alpha[r] + sm;
            m_r[r] = mnew;
        }
        // rescale O
        #pragma unroll
        for (int t = 0; t < 8; t++)
            #pragma unroll
            for (int r = 0; r < 4; r++)
                oacc[t][r] *= alpha[r];
        // write P (C-layout) to LDS as f16
        #pragma unroll
        for (int f = 0; f < 2; f++)
            #pragma unroll
            for (int r = 0; r < 4; r++)
                Ps[wave][(quad * 4 + r) * PS + f * 16 + lrow] = (half_t)pk[f][r];
        __syncthreads();
        // PV: A = P (A-layout read), B = Vt
        halfx8 pa = *(const halfx8*)&Ps[wave][lrow * PS + k0];
        #pragma unroll
        for (int t = 0; t < 8; t++) {
            halfx8 bv = *(const halfx8*)&Vt[(t * 16 + lrow) * VS + k0];
            oacc[t] = __builtin_amdgcn_mfma_f32_16x16x32_f16(pa, bv, oacc[t], 0, 0, 0);
        }
    }

    // epilogue: o[row][head*128 + t*16 + lrow] = oacc / l
    #pragma unroll
    for (int r = 0; r < 4; r++) {
        float inv = 1.0f / l_r[r];
        long row = qpos[r];
        #pragma unroll
        for (int t = 0; t < 8; t++)
            o[row * HDIM + head * 128 + t * 16 + lrow] = (half_t)(oacc[t][r] * inv);
    }
}

extern "C" void kernel_launch(void* const* d_in, const int* in_sizes, int n_in,
                              void* d_out, int out_size, void* d_ws, size_t ws_size,
                              hipStream_t stream) {
    const float* hidden = (const float*)d_in[0];
    const float* cosT   = (const float*)d_in[1];
    const float* sinT   = (const float*)d_in[2];
    const int*   doc    = (const int*)d_in[3];
    // d_in[4] = position_ids (unused; cos/sin precomputed)
    const float* Wq = (const float*)d_in[5];
    const float* bq = (const float*)d_in[6];
    const float* Wk = (const float*)d_in[7];
    const float* bk = (const float*)d_in[8];
    const float* Wv = (const float*)d_in[9];
    const float* bv = (const float*)d_in[10];
    const float* Wo = (const float*)d_in[11];
    float* out = (float*)d_out;

    half_t* q = (half_t*)d_ws;                    // 2048*3584
    half_t* k = q + (size_t)S_LEN * HDIM;         // 2048*512
    half_t* v = k + (size_t)S_LEN * KVDIM;        // 2048*512
    half_t* o = v + (size_t)S_LEN * KVDIM;        // 2048*3584

    qkv_kernel<<<dim3(36, 16), 256, 0, stream>>>(hidden, Wq, bq, Wk, bk, Wv, bv, q, k, v);
    rope_kernel<<<16384, 256, 0, stream>>>(q, k, cosT, sinT);
    attn_kernel<<<dim3(32, NHEADS), 256, 0, stream>>>(q, k, v, doc, o);
    oproj_kernel<<<dim3(28, 16), 256, 0, stream>>>(o, Wo, out);
}

// Round 2
// 653.594 us; speedup vs baseline: 1.1887x; 1.1887x over previous
//
#include <hip/hip_runtime.h>

typedef float floatx4 __attribute__((ext_vector_type(4)));
typedef _Float16 half_t;
typedef _Float16 halfx8 __attribute__((ext_vector_type(8)));
typedef _Float16 halfx4 __attribute__((ext_vector_type(4)));

#define S_LEN 2048
#define HDIM 3584
#define NHEADS 28
#define NKVH 4
#define GRP 7
#define DHEAD 128
#define KVDIM 512   // NKVH*DHEAD

// ---------------------------------------------------------------------------
// Shared GEMM tile body: C[m][n] = sum_k A[m][k] * B[n][k] (+ bias[n])
// 128x128 tile, BK=32, 4 waves, each wave 64x64 = 4x4 MFMA 16x16x32 f16.
// OUT_MODE: 0 = fp32 row-major, 1 = f16 row-major, 2 = f16 col-major
// (transposed store, ldc = M; used to emit V^T for attention).
// ---------------------------------------------------------------------------
template<bool A_IS_HALF, int OUT_MODE, bool HAS_BIAS>
__device__ __forceinline__ void gemm_tile(
    const void* __restrict__ Ap, const float* __restrict__ B,
    const float* __restrict__ bias, void* __restrict__ Cp,
    long bm, long bn, long ldc, int K, half_t* As, half_t* Bs)
{
    constexpr int LDSS = 56;
    const int tid  = threadIdx.x;
    const int lane = tid & 63;
    const int wave = tid >> 6;
    const int wm = (wave >> 1) * 64;
    const int wn = (wave & 1) * 64;
    const int lrow = lane & 15;
    const int quad = lane >> 4;
    const int k0 = quad * 8;

    floatx4 acc[4][4] = {};

    for (int kb = 0; kb < K; kb += 32) {
        __syncthreads();
        if constexpr (A_IS_HALF) {
            const half_t* Af = (const half_t*)Ap;
            #pragma unroll
            for (int i = 0; i < 2; i++) {
                int f = tid + i * 256;        // 0..511
                int row = f >> 2;             // 0..127
                int col = (f & 3) * 8;        // 0..24
                *(halfx8*)&As[row * LDSS + col] =
                    *(const halfx8*)&Af[(bm + row) * (long)K + kb + col];
            }
        } else {
            const float* Af = (const float*)Ap;
            #pragma unroll
            for (int i = 0; i < 4; i++) {
                int f = tid + i * 256;        // 0..1023
                int row = f >> 3;             // 0..127
                int col = (f & 7) * 4;        // 0..28
                floatx4 d = *(const floatx4*)&Af[(bm + row) * (long)K + kb + col];
                halfx4 h;
                h[0] = (half_t)d[0]; h[1] = (half_t)d[1];
                h[2] = (half_t)d[2]; h[3] = (half_t)d[3];
                *(halfx4*)&As[row * LDSS + col] = h;
            }
        }
        #pragma unroll
        for (int i = 0; i < 4; i++) {
            int f = tid + i * 256;
            int row = f >> 3;
            int col = (f & 7) * 4;
            floatx4 d = *(const floatx4*)&B[(bn + row) * (long)K + kb + col];
            halfx4 h;
            h[0] = (half_t)d[0]; h[1] = (half_t)d[1];
            h[2] = (half_t)d[2]; h[3] = (half_t)d[3];
            *(halfx4*)&Bs[row * LDSS + col] = h;
        }
        __syncthreads();

        halfx8 af[4], bf[4];
        #pragma unroll
        for (int i = 0; i < 4; i++)
            af[i] = *(const halfx8*)&As[(wm + i * 16 + lrow) * LDSS + k0];
        #pragma unroll
        for (int j = 0; j < 4; j++)
            bf[j] = *(const halfx8*)&Bs[(wn + j * 16 + lrow) * LDSS + k0];
        #pragma unroll
        for (int i = 0; i < 4; i++)
            #pragma unroll
            for (int j = 0; j < 4; j++)
                acc[i][j] = __builtin_amdgcn_mfma_f32_16x16x32_f16(
                    af[i], bf[j], acc[i][j], 0, 0, 0);
    }

    // Epilogue: C/D layout col=lane&15, row=quad*4+reg
    #pragma unroll
    for (int j = 0; j < 4; j++) {
        long col = bn + wn + j * 16 + lrow;
        float bv = HAS_BIAS ? bias[col] : 0.0f;
        #pragma unroll
        for (int i = 0; i < 4; i++) {
            long rbase = bm + wm + i * 16 + quad * 4;
            if constexpr (OUT_MODE == 2) {
                halfx4 h;
                #pragma unroll
                for (int r = 0; r < 4; r++)
                    h[r] = (half_t)(acc[i][j][r] + bv);
                *(halfx4*)&((half_t*)Cp)[col * ldc + rbase] = h;
            } else {
                #pragma unroll
                for (int r = 0; r < 4; r++) {
                    float v = acc[i][j][r] + bv;
                    if constexpr (OUT_MODE == 1)
                        ((half_t*)Cp)[(rbase + r) * ldc + col] = (half_t)v;
                    else
                        ((float*)Cp)[(rbase + r) * ldc + col] = v;
                }
            }
        }
    }
}

// Fused QKV projection: grid (36,16); bx<28 -> Q, <32 -> K, else V (transposed).
__global__ __launch_bounds__(256) void qkv_kernel(
    const float* __restrict__ hidden,
    const float* __restrict__ Wq, const float* __restrict__ bq,
    const float* __restrict__ Wk, const float* __restrict__ bk,
    const float* __restrict__ Wv, const float* __restrict__ bv,
    half_t* __restrict__ q, half_t* __restrict__ k, half_t* __restrict__ vt)
{
    __shared__ half_t As[128 * 56];
    __shared__ half_t Bs[128 * 56];
    int bx = blockIdx.x;
    long bm = (long)blockIdx.y * 128;
    if (bx < 28) {
        gemm_tile<false, 1, true>(hidden, Wq, bq, q, bm, (long)bx * 128,
                                  HDIM, HDIM, As, Bs);
    } else if (bx < 32) {
        gemm_tile<false, 1, true>(hidden, Wk, bk, k, bm, (long)(bx - 28) * 128,
                                  KVDIM, HDIM, As, Bs);
    } else {
        // V, stored transposed: vt[col][row], ldc = S_LEN
        gemm_tile<false, 2, true>(hidden, Wv, bv, vt, bm, (long)(bx - 32) * 128,
                                  S_LEN, HDIM, As, Bs);
    }
}

// Output projection: out = o @ Wo^T (fp32 out)
__global__ __launch_bounds__(256) void oproj_kernel(
    const half_t* __restrict__ o, const float* __restrict__ Wo,
    float* __restrict__ out)
{
    __shared__ half_t As[128 * 56];
    __shared__ half_t Bs[128 * 56];
    gemm_tile<true, 0, false>(o, Wo, nullptr, out,
                              (long)blockIdx.y * 128, (long)blockIdx.x * 128,
                              HDIM, HDIM, As, Bs);
}

// In-place RoPE on q (with 1/sqrt(D) scale folded in) and k.
__global__ __launch_bounds__(256) void rope_kernel(
    half_t* __restrict__ q, half_t* __restrict__ k,
    const float* __restrict__ ct, const float* __restrict__ st)
{
    const float scale = 0.08838834764831845f; // 128^-0.5
    int idx = blockIdx.x * 256 + threadIdx.x;
    const int QP = S_LEN * NHEADS * 64;
    half_t* base; int s, d; float sc;
    if (idx < QP) {
        s = idx / (NHEADS * 64);
        int rem = idx % (NHEADS * 64);
        int h = rem >> 6; d = rem & 63;
        base = q + (long)s * HDIM + h * 128 + d;
        sc = scale;
    } else {
        int j = idx - QP;
        s = j / (NKVH * 64);
        int rem = j % (NKVH * 64);
        int h = rem >> 6; d = rem & 63;
        base = k + (long)s * KVDIM + h * 128 + d;
        sc = 1.0f;
    }
    float c = ct[s * 128 + d], sn = st[s * 128 + d];
    float x1 = (float)base[0], x2 = (float)base[64];
    base[0]  = (half_t)((x1 * c - x2 * sn) * sc);
    base[64] = (half_t)((x2 * c + x1 * sn) * sc);
}

// Flash attention, barrier-free. Block = (64 q rows, 1 head), 4 independent
// waves x 16 rows. 64-key chunks; K and V^T fragments loaded directly from
// global (L2-resident, 2 MB each); only the per-wave P C->A layout roundtrip
// uses LDS (wave-private -> no __syncthreads anywhere).
// Doc-aware start: keys before this doc segment are skipped entirely.
__global__ __launch_bounds__(256) void attn_kernel(
    const half_t* __restrict__ q, const half_t* __restrict__ k,
    const half_t* __restrict__ vt, const int* __restrict__ doc,
    half_t* __restrict__ o)
{
    constexpr int PS = 72; // halves per P row: 64 keys + 8 pad (rows 2-way free)
    __shared__ half_t Ps[4][16 * PS];

    const int tid  = threadIdx.x;
    const int lane = tid & 63;
    const int wave = tid >> 6;
    const int head = blockIdx.y;
    const int kvh  = head / GRP;
    const int qbase = blockIdx.x * 64;
    const int lrow = lane & 15;
    const int quad = lane >> 4;
    const int k0 = quad * 8;

    // Q fragments (rows qbase+wave*16+lrow, d = kk*32 + quad*8 + j)
    const int qrow = qbase + wave * 16 + lrow;
    halfx8 qf[4];
    #pragma unroll
    for (int kk = 0; kk < 4; kk++)
        qf[kk] = *(const halfx8*)&q[(long)qrow * HDIM + head * 128 + kk * 32 + k0];

    int qdoc[4], qpos[4];
    #pragma unroll
    for (int r = 0; r < 4; r++) {
        qpos[r] = qbase + wave * 16 + quad * 4 + r;
        qdoc[r] = doc[qpos[r]];
    }

    // lower_bound(doc, doc[qbase]): first key of the earliest doc in this tile
    int tgt = doc[qbase];
    int lo = 0, hi = qbase;
    while (lo < hi) { int mid = (lo + hi) >> 1; if (doc[mid] < tgt) lo = mid + 1; else hi = mid; }
    const int kc0 = lo & ~63;

    float m_r[4], l_r[4];
    floatx4 oacc[8] = {};
    #pragma unroll
    for (int r = 0; r < 4; r++) { m_r[r] = -INFINITY; l_r[r] = 0.0f; }

    for (int kbase = kc0; kbase <= qbase; kbase += 64) {
        // ---- QK^T: 4 sub-tiles of 16 keys, direct global B-fragments ----
        floatx4 sacc[4] = {};
        #pragma unroll
        for (int s = 0; s < 4; s++) {
            const half_t* kp = &k[(long)(kbase + s * 16 + lrow) * KVDIM + kvh * 128];
            #pragma unroll
            for (int kk = 0; kk < 4; kk++) {
                halfx8 bk = *(const halfx8*)&kp[kk * 32 + k0];
                sacc[s] = __builtin_amdgcn_mfma_f32_16x16x32_f16(qf[kk], bk, sacc[s], 0, 0, 0);
            }
        }

        // ---- mask + online softmax ----
        int kpix[4], kd[4];
        #pragma unroll
        for (int s = 0; s < 4; s++) {
            kpix[s] = kbase + s * 16 + lrow;
            kd[s] = doc[kpix[s]];
        }
        float pk[4][4];
        float alpha[4];
        #pragma unroll
        for (int r = 0; r < 4; r++) {
            float sv[4];
            float mx = -INFINITY;
            #pragma unroll
            for (int s = 0; s < 4; s++) {
                float x = sacc[s][r];
                bool valid = (kpix[s] <= qpos[r]) && (kd[s] == qdoc[r]);
                x = valid ? x : -INFINITY;
                sv[s] = x;
                mx = fmaxf(mx, x);
            }
            #pragma unroll
            for (int off = 1; off < 16; off <<= 1)
                mx = fmaxf(mx, __shfl_xor(mx, off));
            float mnew = fmaxf(m_r[r], mx);
            bool ninf = (mnew != -INFINITY);
            alpha[r] = ninf ? __expf(m_r[r] - mnew) : 1.0f;
            float sm = 0.0f;
            #pragma unroll
            for (int s = 0; s < 4; s++) {
                float p = ninf ? __expf(sv[s] - mnew) : 0.0f;
                pk[s][r] = p;
                sm += p;
            }
            #pragma unroll
            for (int off = 1; off < 16; off <<= 1)
                sm += __shfl_xor(sm, off);
            l_r[r] = l_r[r] * alpha[r] + sm;
            m_r[r] = mnew;
        }

        // rescale O accumulator
        #pragma unroll
        for (int t = 0; t < 8; t++)
            #pragma unroll
            for (int r = 0; r < 4; r++)
                oacc[t][r] *= alpha[r];

        // P: C-layout regs -> wave-private LDS -> A-layout fragments
        #pragma unroll
        for (int s = 0; s < 4; s++)
            #pragma unroll
            for (int r = 0; r < 4; r++)
                Ps[wave][(quad * 4 + r) * PS + s * 16 + lrow] = (half_t)pk[s][r];
        halfx8 pa0 = *(const halfx8*)&Ps[wave][lrow * PS + k0];
        halfx8 pa1 = *(const halfx8*)&Ps[wave][lrow * PS + 32 + k0];

        // ---- PV: direct global V^T B-fragments ----
        #pragma unroll
        for (int t = 0; t < 8; t++) {
            const half_t* vp = &vt[(long)(kvh * 128 + t * 16 + lrow) * S_LEN + kbase];
            halfx8 b0 = *(const halfx8*)&vp[k0];
            halfx8 b1 = *(const halfx8*)&vp[32 + k0];
            oacc[t] = __builtin_amdgcn_mfma_f32_16x16x32_f16(pa0, b0, oacc[t], 0, 0, 0);
            oacc[t] = __builtin_amdgcn_mfma_f32_16x16x32_f16(pa1, b1, oacc[t], 0, 0, 0);
        }
    }

    // epilogue
    #pragma unroll
    for (int r = 0; r < 4; r++) {
        float inv = 1.0f / l_r[r];
        long row = qpos[r];
        #pragma unroll
        for (int t = 0; t < 8; t++)
            o[row * HDIM + head * 128 + t * 16 + lrow] = (half_t)(oacc[t][r] * inv);
    }
}

extern "C" void kernel_launch(void* const* d_in, const int* in_sizes, int n_in,
                              void* d_out, int out_size, void* d_ws, size_t ws_size,
                              hipStream_t stream) {
    const float* hidden = (const float*)d_in[0];
    const float* cosT   = (const float*)d_in[1];
    const float* sinT   = (const float*)d_in[2];
    const int*   doc    = (const int*)d_in[3];
    // d_in[4] = position_ids (unused; cos/sin precomputed)
    const float* Wq = (const float*)d_in[5];
    const float* bq = (const float*)d_in[6];
    const float* Wk = (const float*)d_in[7];
    const float* bk = (const float*)d_in[8];
    const float* Wv = (const float*)d_in[9];
    const float* bv = (const float*)d_in[10];
    const float* Wo = (const float*)d_in[11];
    float* out = (float*)d_out;

    half_t* q  = (half_t*)d_ws;                    // 2048*3584
    half_t* k  = q + (size_t)S_LEN * HDIM;         // 2048*512
    half_t* vt = k + (size_t)S_LEN * KVDIM;        // 512*2048 (transposed)
    half_t* o  = vt + (size_t)KVDIM * S_LEN;       // 2048*3584

    qkv_kernel<<<dim3(36, 16), 256, 0, stream>>>(hidden, Wq, bq, Wk, bk, Wv, bv, q, k, vt);
    rope_kernel<<<16384, 256, 0, stream>>>(q, k, cosT, sinT);
    attn_kernel<<<dim3(32, NHEADS), 256, 0, stream>>>(q, k, vt, doc, o);
    oproj_kernel<<<dim3(28, 16), 256, 0, stream>>>(o, Wo, out);
}

// Round 3
// 501.712 us; speedup vs baseline: 1.5486x; 1.3027x over previous
//
#include <hip/hip_runtime.h>

typedef float floatx4 __attribute__((ext_vector_type(4)));
typedef _Float16 half_t;
typedef _Float16 halfx8 __attribute__((ext_vector_type(8)));
typedef _Float16 halfx4 __attribute__((ext_vector_type(4)));

#define S_LEN 2048
#define HDIM 3584
#define NHEADS 28
#define NKVH 4
#define GRP 7
#define DHEAD 128
#define KVDIM 512   // NKVH*DHEAD

// Async global->LDS, 16B per lane. LDS dest is wave-uniform base + lane*16;
// our LDS layouts are contiguous in lane order (no padding) to satisfy this.
__device__ __forceinline__ void load_lds16(const half_t* g, half_t* l) {
    __builtin_amdgcn_global_load_lds(
        (__attribute__((address_space(1))) void*)(g),
        (__attribute__((address_space(3))) void*)(l), 16, 0, 0);
}

// ---------------------------------------------------------------------------
// fp32 -> f16 conversion for hidden + all weights, one launch.
// Region boundaries in 8192-element blocks (sizes are compile-time fixed).
// ---------------------------------------------------------------------------
__global__ __launch_bounds__(256) void cvt_kernel(
    const float* __restrict__ hidden, const float* __restrict__ Wq,
    const float* __restrict__ Wk, const float* __restrict__ Wv,
    const float* __restrict__ Wo,
    half_t* __restrict__ hh, half_t* __restrict__ wq, half_t* __restrict__ wk,
    half_t* __restrict__ wv, half_t* __restrict__ wo)
{
    int b = blockIdx.x;
    const float* src; half_t* dst; long off;
    if (b < 896)       { src = hidden; dst = hh; off = (long)b * 8192; }
    else if (b < 2464) { src = Wq; dst = wq; off = (long)(b - 896) * 8192; }
    else if (b < 2688) { src = Wk; dst = wk; off = (long)(b - 2464) * 8192; }
    else if (b < 2912) { src = Wv; dst = wv; off = (long)(b - 2688) * 8192; }
    else               { src = Wo; dst = wo; off = (long)(b - 2912) * 8192; }
    #pragma unroll
    for (int i = 0; i < 8; i++) {
        long e = off + i * 1024 + threadIdx.x * 4;
        floatx4 d = *(const floatx4*)&src[e];
        halfx4 h;
        h[0] = (half_t)d[0]; h[1] = (half_t)d[1];
        h[2] = (half_t)d[2]; h[3] = (half_t)d[3];
        *(halfx4*)&dst[e] = h;
    }
}

// ---------------------------------------------------------------------------
// m97-structure f16 GEMM tile: C[m][n] = sum_k A[m][k]*B[n][k] (+bias[n]).
// 128x128 tile, BK=32, 4 waves x 4x4 MFMA 16x16x32 f16.
// Staging via global_load_lds width=16; LDS row-major 128x32 contiguous.
// OUT_MODE: 0 = fp32 row-major, 1 = f16 row-major, 2 = f16 col-major (ldc=M).
// ---------------------------------------------------------------------------
template<int OUT_MODE, bool HAS_BIAS>
__device__ __forceinline__ void gemm_f16(
    const half_t* __restrict__ A, const half_t* __restrict__ B,
    const float* __restrict__ bias, void* __restrict__ Cp,
    long bm, long bn, long ldc, int K, half_t* As, half_t* Bs)
{
    const int tid  = threadIdx.x;
    const int lane = tid & 63;
    const int wave = tid >> 6;
    const int wm = (wave >> 1) * 64;
    const int wn = (wave & 1) * 64;
    const int lrow = lane & 15;
    const int quad = lane >> 4;
    const int k0q = quad * 8;

    // staging thread map: chunk f covers row f>>2, cols (f&3)*8 .. +8
    const int r0 = tid >> 2;
    const int c0 = (tid & 3) * 8;
    const half_t* a0 = &A[(bm + r0) * (long)K + c0];
    const half_t* a1 = a0 + 64 * (long)K;
    const half_t* b0 = &B[(bn + r0) * (long)K + c0];
    const half_t* b1 = b0 + 64 * (long)K;
    half_t* lA0 = &As[tid * 8];
    half_t* lA1 = lA0 + 2048;
    half_t* lB0 = &Bs[tid * 8];
    half_t* lB1 = lB0 + 2048;

    floatx4 acc[4][4] = {};

    for (int kb = 0; kb < K; kb += 32) {
        __syncthreads();   // all waves done reading LDS from prior iter
        load_lds16(a0 + kb, lA0);
        load_lds16(a1 + kb, lA1);
        load_lds16(b0 + kb, lB0);
        load_lds16(b1 + kb, lB1);
        __syncthreads();   // drains vmcnt -> staged data visible

        halfx8 af[4], bf[4];
        #pragma unroll
        for (int i = 0; i < 4; i++)
            af[i] = *(const halfx8*)&As[(wm + i * 16 + lrow) * 32 + k0q];
        #pragma unroll
        for (int j = 0; j < 4; j++)
            bf[j] = *(const halfx8*)&Bs[(wn + j * 16 + lrow) * 32 + k0q];
        #pragma unroll
        for (int i = 0; i < 4; i++)
            #pragma unroll
            for (int j = 0; j < 4; j++)
                acc[i][j] = __builtin_amdgcn_mfma_f32_16x16x32_f16(
                    af[i], bf[j], acc[i][j], 0, 0, 0);
    }

    // Epilogue: C/D layout col=lane&15, row=quad*4+reg
    #pragma unroll
    for (int j = 0; j < 4; j++) {
        long col = bn + wn + j * 16 + lrow;
        float bv = HAS_BIAS ? bias[col] : 0.0f;
        #pragma unroll
        for (int i = 0; i < 4; i++) {
            long rbase = bm + wm + i * 16 + quad * 4;
            if constexpr (OUT_MODE == 2) {
                halfx4 h;
                #pragma unroll
                for (int r = 0; r < 4; r++)
                    h[r] = (half_t)(acc[i][j][r] + bv);
                *(halfx4*)&((half_t*)Cp)[col * ldc + rbase] = h;
            } else {
                #pragma unroll
                for (int r = 0; r < 4; r++) {
                    float v = acc[i][j][r] + bv;
                    if constexpr (OUT_MODE == 1)
                        ((half_t*)Cp)[(rbase + r) * ldc + col] = (half_t)v;
                    else
                        ((float*)Cp)[(rbase + r) * ldc + col] = v;
                }
            }
        }
    }
}

// Fused QKV projection: grid (36,16); bx<28 -> Q, <32 -> K, else V^T.
__global__ __launch_bounds__(256) void qkv_kernel(
    const half_t* __restrict__ hh,
    const half_t* __restrict__ wq, const float* __restrict__ bq,
    const half_t* __restrict__ wk, const float* __restrict__ bk,
    const half_t* __restrict__ wv, const float* __restrict__ bv,
    half_t* __restrict__ q, half_t* __restrict__ k, half_t* __restrict__ vt)
{
    __shared__ half_t As[128 * 32];
    __shared__ half_t Bs[128 * 32];
    int bx = blockIdx.x;
    long bm = (long)blockIdx.y * 128;
    if (bx < 28) {
        gemm_f16<1, true>(hh, wq, bq, q, bm, (long)bx * 128, HDIM, HDIM, As, Bs);
    } else if (bx < 32) {
        gemm_f16<1, true>(hh, wk, bk, k, bm, (long)(bx - 28) * 128, KVDIM, HDIM, As, Bs);
    } else {
        gemm_f16<2, true>(hh, wv, bv, vt, bm, (long)(bx - 32) * 128, S_LEN, HDIM, As, Bs);
    }
}

// Output projection: out = o @ Wo^T (fp32 out)
__global__ __launch_bounds__(256) void oproj_kernel(
    const half_t* __restrict__ o, const half_t* __restrict__ wo,
    float* __restrict__ out)
{
    __shared__ half_t As[128 * 32];
    __shared__ half_t Bs[128 * 32];
    gemm_f16<0, false>(o, wo, nullptr, out,
                       (long)blockIdx.y * 128, (long)blockIdx.x * 128,
                       HDIM, HDIM, As, Bs);
}

// In-place RoPE on q (with 1/sqrt(D) scale folded in) and k.
__global__ __launch_bounds__(256) void rope_kernel(
    half_t* __restrict__ q, half_t* __restrict__ k,
    const float* __restrict__ ct, const float* __restrict__ st)
{
    const float scale = 0.08838834764831845f; // 128^-0.5
    int idx = blockIdx.x * 256 + threadIdx.x;
    const int QP = S_LEN * NHEADS * 64;
    half_t* base; int s, d; float sc;
    if (idx < QP) {
        s = idx / (NHEADS * 64);
        int rem = idx % (NHEADS * 64);
        int h = rem >> 6; d = rem & 63;
        base = q + (long)s * HDIM + h * 128 + d;
        sc = scale;
    } else {
        int j = idx - QP;
        s = j / (NKVH * 64);
        int rem = j % (NKVH * 64);
        int h = rem >> 6; d = rem & 63;
        base = k + (long)s * KVDIM + h * 128 + d;
        sc = 1.0f;
    }
    float c = ct[s * 128 + d], sn = st[s * 128 + d];
    float x1 = (float)base[0], x2 = (float)base[64];
    base[0]  = (half_t)((x1 * c - x2 * sn) * sc);
    base[64] = (half_t)((x2 * c + x1 * sn) * sc);
}

// Flash attention, barrier-free. Block = (64 q rows, 1 head), 4 independent
// waves x 16 rows. 64-key chunks; K and V^T fragments loaded directly from
// global (L2-resident); only the per-wave P C->A roundtrip uses LDS.
__global__ __launch_bounds__(256) void attn_kernel(
    const half_t* __restrict__ q, const half_t* __restrict__ k,
    const half_t* __restrict__ vt, const int* __restrict__ doc,
    half_t* __restrict__ o)
{
    constexpr int PS = 72; // 64 keys + 8 pad
    __shared__ half_t Ps[4][16 * PS];

    const int tid  = threadIdx.x;
    const int lane = tid & 63;
    const int wave = tid >> 6;
    const int head = blockIdx.y;
    const int kvh  = head / GRP;
    const int qbase = blockIdx.x * 64;
    const int lrow = lane & 15;
    const int quad = lane >> 4;
    const int k0 = quad * 8;

    const int qrow = qbase + wave * 16 + lrow;
    halfx8 qf[4];
    #pragma unroll
    for (int kk = 0; kk < 4; kk++)
        qf[kk] = *(const halfx8*)&q[(long)qrow * HDIM + head * 128 + kk * 32 + k0];

    int qdoc[4], qpos[4];
    #pragma unroll
    for (int r = 0; r < 4; r++) {
        qpos[r] = qbase + wave * 16 + quad * 4 + r;
        qdoc[r] = doc[qpos[r]];
    }

    // lower_bound(doc, doc[qbase]): skip keys before this tile's earliest doc
    int tgt = doc[qbase];
    int lo = 0, hi = qbase;
    while (lo < hi) { int mid = (lo + hi) >> 1; if (doc[mid] < tgt) lo = mid + 1; else hi = mid; }
    const int kc0 = lo & ~63;

    float m_r[4], l_r[4];
    floatx4 oacc[8] = {};
    #pragma unroll
    for (int r = 0; r < 4; r++) { m_r[r] = -INFINITY; l_r[r] = 0.0f; }

    for (int kbase = kc0; kbase <= qbase; kbase += 64) {
        floatx4 sacc[4] = {};
        #pragma unroll
        for (int s = 0; s < 4; s++) {
            const half_t* kp = &k[(long)(kbase + s * 16 + lrow) * KVDIM + kvh * 128];
            #pragma unroll
            for (int kk = 0; kk < 4; kk++) {
                halfx8 bk = *(const halfx8*)&kp[kk * 32 + k0];
                sacc[s] = __builtin_amdgcn_mfma_f32_16x16x32_f16(qf[kk], bk, sacc[s], 0, 0, 0);
            }
        }

        int kpix[4], kd[4];
        #pragma unroll
        for (int s = 0; s < 4; s++) {
            kpix[s] = kbase + s * 16 + lrow;
            kd[s] = doc[kpix[s]];
        }
        float pk[4][4];
        float alpha[4];
        #pragma unroll
        for (int r = 0; r < 4; r++) {
            float sv[4];
            float mx = -INFINITY;
            #pragma unroll
            for (int s = 0; s < 4; s++) {
                float x = sacc[s][r];
                bool valid = (kpix[s] <= qpos[r]) && (kd[s] == qdoc[r]);
                x = valid ? x : -INFINITY;
                sv[s] = x;
                mx = fmaxf(mx, x);
            }
            #pragma unroll
            for (int off = 1; off < 16; off <<= 1)
                mx = fmaxf(mx, __shfl_xor(mx, off));
            float mnew = fmaxf(m_r[r], mx);
            bool ninf = (mnew != -INFINITY);
            alpha[r] = ninf ? __expf(m_r[r] - mnew) : 1.0f;
            float sm = 0.0f;
            #pragma unroll
            for (int s = 0; s < 4; s++) {
                float p = ninf ? __expf(sv[s] - mnew) : 0.0f;
                pk[s][r] = p;
                sm += p;
            }
            #pragma unroll
            for (int off = 1; off < 16; off <<= 1)
                sm += __shfl_xor(sm, off);
            l_r[r] = l_r[r] * alpha[r] + sm;
            m_r[r] = mnew;
        }

        #pragma unroll
        for (int t = 0; t < 8; t++)
            #pragma unroll
            for (int r = 0; r < 4; r++)
                oacc[t][r] *= alpha[r];

        #pragma unroll
        for (int s = 0; s < 4; s++)
            #pragma unroll
            for (int r = 0; r < 4; r++)
                Ps[wave][(quad * 4 + r) * PS + s * 16 + lrow] = (half_t)pk[s][r];
        halfx8 pa0 = *(const halfx8*)&Ps[wave][lrow * PS + k0];
        halfx8 pa1 = *(const halfx8*)&Ps[wave][lrow * PS + 32 + k0];

        #pragma unroll
        for (int t = 0; t < 8; t++) {
            const half_t* vp = &vt[(long)(kvh * 128 + t * 16 + lrow) * S_LEN + kbase];
            halfx8 b0 = *(const halfx8*)&vp[k0];
            halfx8 b1 = *(const halfx8*)&vp[32 + k0];
            oacc[t] = __builtin_amdgcn_mfma_f32_16x16x32_f16(pa0, b0, oacc[t], 0, 0, 0);
            oacc[t] = __builtin_amdgcn_mfma_f32_16x16x32_f16(pa1, b1, oacc[t], 0, 0, 0);
        }
    }

    #pragma unroll
    for (int r = 0; r < 4; r++) {
        float inv = 1.0f / l_r[r];
        long row = qpos[r];
        #pragma unroll
        for (int t = 0; t < 8; t++)
            o[row * HDIM + head * 128 + t * 16 + lrow] = (half_t)(oacc[t][r] * inv);
    }
}

extern "C" void kernel_launch(void* const* d_in, const int* in_sizes, int n_in,
                              void* d_out, int out_size, void* d_ws, size_t ws_size,
                              hipStream_t stream) {
    const float* hidden = (const float*)d_in[0];
    const float* cosT   = (const float*)d_in[1];
    const float* sinT   = (const float*)d_in[2];
    const int*   doc    = (const int*)d_in[3];
    // d_in[4] = position_ids (unused; cos/sin precomputed)
    const float* Wq = (const float*)d_in[5];
    const float* bq = (const float*)d_in[6];
    const float* Wk = (const float*)d_in[7];
    const float* bk = (const float*)d_in[8];
    const float* Wv = (const float*)d_in[9];
    const float* bv = (const float*)d_in[10];
    const float* Wo = (const float*)d_in[11];
    float* out = (float*)d_out;

    // f16 workspace layout (halves)
    half_t* hh  = (half_t*)d_ws;                   // 2048*3584 (dead after qkv; o reuses it)
    half_t* q   = hh  + (size_t)S_LEN * HDIM;
    half_t* k   = q   + (size_t)S_LEN * HDIM;
    half_t* vt  = k   + (size_t)S_LEN * KVDIM;
    half_t* wqh = vt  + (size_t)KVDIM * S_LEN;
    half_t* wkh = wqh + (size_t)HDIM * HDIM;
    half_t* wvh = wkh + (size_t)KVDIM * HDIM;
    half_t* woh = wvh + (size_t)KVDIM * HDIM;
    half_t* o   = hh; // alias: hh is dead once qkv_kernel completes

    cvt_kernel<<<4480, 256, 0, stream>>>(hidden, Wq, Wk, Wv, Wo, hh, wqh, wkh, wvh, woh);
    qkv_kernel<<<dim3(36, 16), 256, 0, stream>>>(hh, wqh, bq, wkh, bk, wvh, bv, q, k, vt);
    rope_kernel<<<16384, 256, 0, stream>>>(q, k, cosT, sinT);
    attn_kernel<<<dim3(32, NHEADS), 256, 0, stream>>>(q, k, vt, doc, o);
    oproj_kernel<<<dim3(28, 16), 256, 0, stream>>>(o, woh, out);
}

// Round 4
// 492.860 us; speedup vs baseline: 1.5764x; 1.0180x over previous
//
#include <hip/hip_runtime.h>

typedef float floatx4 __attribute__((ext_vector_type(4)));
typedef _Float16 half_t;
typedef _Float16 halfx8 __attribute__((ext_vector_type(8)));
typedef _Float16 halfx4 __attribute__((ext_vector_type(4)));

#define S_LEN 2048
#define HDIM 3584
#define NHEADS 28
#define NKVH 4
#define GRP 7
#define DHEAD 128
#define KVDIM 512   // NKVH*DHEAD

// Async global->LDS, 16B per lane. LDS dest is wave-uniform base + lane*16.
__device__ __forceinline__ void load_lds16(const half_t* g, half_t* l) {
    __builtin_amdgcn_global_load_lds(
        (__attribute__((address_space(1))) void*)(g),
        (__attribute__((address_space(3))) void*)(l), 16, 0, 0);
}

// ---------------------------------------------------------------------------
// fp32 -> f16 conversion for hidden + all weights, one launch.
// ---------------------------------------------------------------------------
__global__ __launch_bounds__(256) void cvt_kernel(
    const float* __restrict__ hidden, const float* __restrict__ Wq,
    const float* __restrict__ Wk, const float* __restrict__ Wv,
    const float* __restrict__ Wo,
    half_t* __restrict__ hh, half_t* __restrict__ wq, half_t* __restrict__ wk,
    half_t* __restrict__ wv, half_t* __restrict__ wo)
{
    int b = blockIdx.x;
    const float* src; half_t* dst; long off;
    if (b < 896)       { src = hidden; dst = hh; off = (long)b * 8192; }
    else if (b < 2464) { src = Wq; dst = wq; off = (long)(b - 896) * 8192; }
    else if (b < 2688) { src = Wk; dst = wk; off = (long)(b - 2464) * 8192; }
    else if (b < 2912) { src = Wv; dst = wv; off = (long)(b - 2688) * 8192; }
    else               { src = Wo; dst = wo; off = (long)(b - 2912) * 8192; }
    #pragma unroll
    for (int i = 0; i < 8; i++) {
        long e = off + i * 1024 + threadIdx.x * 4;
        floatx4 d = *(const floatx4*)&src[e];
        halfx4 h;
        h[0] = (half_t)d[0]; h[1] = (half_t)d[1];
        h[2] = (half_t)d[2]; h[3] = (half_t)d[3];
        *(halfx4*)&dst[e] = h;
    }
}

// ---------------------------------------------------------------------------
// Double-buffered f16 GEMM tile: C[m][n] = sum_k A[m][k]*B[n][k] (+bias[n]).
// 128x128 tile, BK=32, 4 waves x 4x4 MFMA 16x16x32 f16.
// One barrier per K-iter: barrier ensures tile t staged (vmcnt0 drain) AND
// buf[(t+1)&1] is free; then tile t+1 is prefetched while computing tile t,
// so each global_load_lds has a full compute phase in flight.
// As/Bs are 2 x (128x32) halves each (32 KB LDS total).
// OUT_MODE: 0 = fp32 row-major, 1 = f16 row-major, 2 = f16 col-major (ldc=M).
// ---------------------------------------------------------------------------
template<int OUT_MODE, bool HAS_BIAS>
__device__ __forceinline__ void gemm_f16(
    const half_t* __restrict__ A, const half_t* __restrict__ B,
    const float* __restrict__ bias, void* __restrict__ Cp,
    long bm, long bn, long ldc, int K, half_t* As, half_t* Bs)
{
    const int tid  = threadIdx.x;
    const int lane = tid & 63;
    const int wave = tid >> 6;
    const int wm = (wave >> 1) * 64;
    const int wn = (wave & 1) * 64;
    const int lrow = lane & 15;
    const int quad = lane >> 4;
    const int k0q = quad * 8;

    // staging map: chunk tid covers row tid>>2, cols (tid&3)*8 .. +8
    const int r0 = tid >> 2;
    const int c0 = (tid & 3) * 8;
    const half_t* a0 = &A[(bm + r0) * (long)K + c0];
    const half_t* a1 = a0 + 64 * (long)K;
    const half_t* b0 = &B[(bn + r0) * (long)K + c0];
    const half_t* b1 = b0 + 64 * (long)K;

    floatx4 acc[4][4] = {};

    // prologue: tile 0 -> buffer 0
    load_lds16(a0, &As[tid * 8]);
    load_lds16(a1, &As[2048 + tid * 8]);
    load_lds16(b0, &Bs[tid * 8]);
    load_lds16(b1, &Bs[2048 + tid * 8]);

    const int nk = K >> 5;
    for (int t = 0; t < nk; t++) {
        __syncthreads();   // tile t arrived; all waves done reading buf[(t+1)&1]
        if (t + 1 < nk) {
            const int kb = (t + 1) << 5;
            const int nb = ((t + 1) & 1) * 4096;
            load_lds16(a0 + kb, &As[nb + tid * 8]);
            load_lds16(a1 + kb, &As[nb + 2048 + tid * 8]);
            load_lds16(b0 + kb, &Bs[nb + tid * 8]);
            load_lds16(b1 + kb, &Bs[nb + 2048 + tid * 8]);
        }
        const half_t* cA = &As[(t & 1) * 4096];
        const half_t* cB = &Bs[(t & 1) * 4096];
        halfx8 af[4], bf[4];
        #pragma unroll
        for (int i = 0; i < 4; i++)
            af[i] = *(const halfx8*)&cA[(wm + i * 16 + lrow) * 32 + k0q];
        #pragma unroll
        for (int j = 0; j < 4; j++)
            bf[j] = *(const halfx8*)&cB[(wn + j * 16 + lrow) * 32 + k0q];
        #pragma unroll
        for (int i = 0; i < 4; i++)
            #pragma unroll
            for (int j = 0; j < 4; j++)
                acc[i][j] = __builtin_amdgcn_mfma_f32_16x16x32_f16(
                    af[i], bf[j], acc[i][j], 0, 0, 0);
    }

    // Epilogue: C/D layout col=lane&15, row=quad*4+reg
    #pragma unroll
    for (int j = 0; j < 4; j++) {
        long col = bn + wn + j * 16 + lrow;
        float bv = HAS_BIAS ? bias[col] : 0.0f;
        #pragma unroll
        for (int i = 0; i < 4; i++) {
            long rbase = bm + wm + i * 16 + quad * 4;
            if constexpr (OUT_MODE == 2) {
                halfx4 h;
                #pragma unroll
                for (int r = 0; r < 4; r++)
                    h[r] = (half_t)(acc[i][j][r] + bv);
                *(halfx4*)&((half_t*)Cp)[col * ldc + rbase] = h;
            } else {
                #pragma unroll
                for (int r = 0; r < 4; r++) {
                    float v = acc[i][j][r] + bv;
                    if constexpr (OUT_MODE == 1)
                        ((half_t*)Cp)[(rbase + r) * ldc + col] = (half_t)v;
                    else
                        ((float*)Cp)[(rbase + r) * ldc + col] = v;
                }
            }
        }
    }
}

// Fused QKV projection: grid (16, 36); x = row-tile (L2/XCD locality:
// concurrent blocks share the weight tile, hidden row-tile x pins to XCD x%8),
// y = col-tile: y<28 -> Q, <32 -> K, else V^T.
__global__ __launch_bounds__(256) void qkv_kernel(
    const half_t* __restrict__ hh,
    const half_t* __restrict__ wq, const float* __restrict__ bq,
    const half_t* __restrict__ wk, const float* __restrict__ bk,
    const half_t* __restrict__ wv, const float* __restrict__ bv,
    half_t* __restrict__ q, half_t* __restrict__ k, half_t* __restrict__ vt)
{
    __shared__ half_t As[2 * 128 * 32];
    __shared__ half_t Bs[2 * 128 * 32];
    int by = blockIdx.y;
    long bm = (long)blockIdx.x * 128;
    if (by < 28) {
        gemm_f16<1, true>(hh, wq, bq, q, bm, (long)by * 128, HDIM, HDIM, As, Bs);
    } else if (by < 32) {
        gemm_f16<1, true>(hh, wk, bk, k, bm, (long)(by - 28) * 128, KVDIM, HDIM, As, Bs);
    } else {
        gemm_f16<2, true>(hh, wv, bv, vt, bm, (long)(by - 32) * 128, S_LEN, HDIM, As, Bs);
    }
}

// Output projection: out = o @ Wo^T (fp32 out). grid (16, 28), x = row-tile.
__global__ __launch_bounds__(256) void oproj_kernel(
    const half_t* __restrict__ o, const half_t* __restrict__ wo,
    float* __restrict__ out)
{
    __shared__ half_t As[2 * 128 * 32];
    __shared__ half_t Bs[2 * 128 * 32];
    gemm_f16<0, false>(o, wo, nullptr, out,
                       (long)blockIdx.x * 128, (long)blockIdx.y * 128,
                       HDIM, HDIM, As, Bs);
}

// In-place RoPE on q (with 1/sqrt(D) scale folded in) and k.
__global__ __launch_bounds__(256) void rope_kernel(
    half_t* __restrict__ q, half_t* __restrict__ k,
    const float* __restrict__ ct, const float* __restrict__ st)
{
    const float scale = 0.08838834764831845f; // 128^-0.5
    int idx = blockIdx.x * 256 + threadIdx.x;
    const int QP = S_LEN * NHEADS * 64;
    half_t* base; int s, d; float sc;
    if (idx < QP) {
        s = idx / (NHEADS * 64);
        int rem = idx % (NHEADS * 64);
        int h = rem >> 6; d = rem & 63;
        base = q + (long)s * HDIM + h * 128 + d;
        sc = scale;
    } else {
        int j = idx - QP;
        s = j / (NKVH * 64);
        int rem = j % (NKVH * 64);
        int h = rem >> 6; d = rem & 63;
        base = k + (long)s * KVDIM + h * 128 + d;
        sc = 1.0f;
    }
    float c = ct[s * 128 + d], sn = st[s * 128 + d];
    float x1 = (float)base[0], x2 = (float)base[64];
    base[0]  = (half_t)((x1 * c - x2 * sn) * sc);
    base[64] = (half_t)((x2 * c + x1 * sn) * sc);
}

// Flash attention, barrier-free. Block = (64 q rows, 1 head), 4 independent
// waves x 16 rows. 64-key chunks; K and V^T fragments loaded directly from
// global (L2-resident); only the per-wave P C->A roundtrip uses LDS.
__global__ __launch_bounds__(256) void attn_kernel(
    const half_t* __restrict__ q, const half_t* __restrict__ k,
    const half_t* __restrict__ vt, const int* __restrict__ doc,
    half_t* __restrict__ o)
{
    constexpr int PS = 72; // 64 keys + 8 pad
    __shared__ half_t Ps[4][16 * PS];

    const int tid  = threadIdx.x;
    const int lane = tid & 63;
    const int wave = tid >> 6;
    const int head = blockIdx.y;
    const int kvh  = head / GRP;
    const int qbase = blockIdx.x * 64;
    const int lrow = lane & 15;
    const int quad = lane >> 4;
    const int k0 = quad * 8;

    const int qrow = qbase + wave * 16 + lrow;
    halfx8 qf[4];
    #pragma unroll
    for (int kk = 0; kk < 4; kk++)
        qf[kk] = *(const halfx8*)&q[(long)qrow * HDIM + head * 128 + kk * 32 + k0];

    int qdoc[4], qpos[4];
    #pragma unroll
    for (int r = 0; r < 4; r++) {
        qpos[r] = qbase + wave * 16 + quad * 4 + r;
        qdoc[r] = doc[qpos[r]];
    }

    // lower_bound(doc, doc[qbase]): skip keys before this tile's earliest doc
    int tgt = doc[qbase];
    int lo = 0, hi = qbase;
    while (lo < hi) { int mid = (lo + hi) >> 1; if (doc[mid] < tgt) lo = mid + 1; else hi = mid; }
    const int kc0 = lo & ~63;

    float m_r[4], l_r[4];
    floatx4 oacc[8] = {};
    #pragma unroll
    for (int r = 0; r < 4; r++) { m_r[r] = -INFINITY; l_r[r] = 0.0f; }

    for (int kbase = kc0; kbase <= qbase; kbase += 64) {
        floatx4 sacc[4] = {};
        #pragma unroll
        for (int s = 0; s < 4; s++) {
            const half_t* kp = &k[(long)(kbase + s * 16 + lrow) * KVDIM + kvh * 128];
            #pragma unroll
            for (int kk = 0; kk < 4; kk++) {
                halfx8 bk = *(const halfx8*)&kp[kk * 32 + k0];
                sacc[s] = __builtin_amdgcn_mfma_f32_16x16x32_f16(qf[kk], bk, sacc[s], 0, 0, 0);
            }
        }

        int kpix[4], kd[4];
        #pragma unroll
        for (int s = 0; s < 4; s++) {
            kpix[s] = kbase + s * 16 + lrow;
            kd[s] = doc[kpix[s]];
        }
        float pk[4][4];
        float alpha[4];
        #pragma unroll
        for (int r = 0; r < 4; r++) {
            float sv[4];
            float mx = -INFINITY;
            #pragma unroll
            for (int s = 0; s < 4; s++) {
                float x = sacc[s][r];
                bool valid = (kpix[s] <= qpos[r]) && (kd[s] == qdoc[r]);
                x = valid ? x : -INFINITY;
                sv[s] = x;
                mx = fmaxf(mx, x);
            }
            #pragma unroll
            for (int off = 1; off < 16; off <<= 1)
                mx = fmaxf(mx, __shfl_xor(mx, off));
            float mnew = fmaxf(m_r[r], mx);
            bool ninf = (mnew != -INFINITY);
            alpha[r] = ninf ? __expf(m_r[r] - mnew) : 1.0f;
            float sm = 0.0f;
            #pragma unroll
            for (int s = 0; s < 4; s++) {
                float p = ninf ? __expf(sv[s] - mnew) : 0.0f;
                pk[s][r] = p;
                sm += p;
            }
            #pragma unroll
            for (int off = 1; off < 16; off <<= 1)
                sm += __shfl_xor(sm, off);
            l_r[r] = l_r[r] * alpha[r] + sm;
            m_r[r] = mnew;
        }

        #pragma unroll
        for (int t = 0; t < 8; t++)
            #pragma unroll
            for (int r = 0; r < 4; r++)
                oacc[t][r] *= alpha[r];

        #pragma unroll
        for (int s = 0; s < 4; s++)
            #pragma unroll
            for (int r = 0; r < 4; r++)
                Ps[wave][(quad * 4 + r) * PS + s * 16 + lrow] = (half_t)pk[s][r];
        halfx8 pa0 = *(const halfx8*)&Ps[wave][lrow * PS + k0];
        halfx8 pa1 = *(const halfx8*)&Ps[wave][lrow * PS + 32 + k0];

        #pragma unroll
        for (int t = 0; t < 8; t++) {
            const half_t* vp = &vt[(long)(kvh * 128 + t * 16 + lrow) * S_LEN + kbase];
            halfx8 b0 = *(const halfx8*)&vp[k0];
            halfx8 b1 = *(const halfx8*)&vp[32 + k0];
            oacc[t] = __builtin_amdgcn_mfma_f32_16x16x32_f16(pa0, b0, oacc[t], 0, 0, 0);
            oacc[t] = __builtin_amdgcn_mfma_f32_16x16x32_f16(pa1, b1, oacc[t], 0, 0, 0);
        }
    }

    #pragma unroll
    for (int r = 0; r < 4; r++) {
        float inv = 1.0f / l_r[r];
        long row = qpos[r];
        #pragma unroll
        for (int t = 0; t < 8; t++)
            o[row * HDIM + head * 128 + t * 16 + lrow] = (half_t)(oacc[t][r] * inv);
    }
}

extern "C" void kernel_launch(void* const* d_in, const int* in_sizes, int n_in,
                              void* d_out, int out_size, void* d_ws, size_t ws_size,
                              hipStream_t stream) {
    const float* hidden = (const float*)d_in[0];
    const float* cosT   = (const float*)d_in[1];
    const float* sinT   = (const float*)d_in[2];
    const int*   doc    = (const int*)d_in[3];
    // d_in[4] = position_ids (unused; cos/sin precomputed)
    const float* Wq = (const float*)d_in[5];
    const float* bq = (const float*)d_in[6];
    const float* Wk = (const float*)d_in[7];
    const float* bk = (const float*)d_in[8];
    const float* Wv = (const float*)d_in[9];
    const float* bv = (const float*)d_in[10];
    const float* Wo = (const float*)d_in[11];
    float* out = (float*)d_out;

    // f16 workspace layout (halves)
    half_t* hh  = (half_t*)d_ws;                   // 2048*3584 (dead after qkv; o reuses it)
    half_t* q   = hh  + (size_t)S_LEN * HDIM;
    half_t* k   = q   + (size_t)S_LEN * HDIM;
    half_t* vt  = k   + (size_t)S_LEN * KVDIM;
    half_t* wqh = vt  + (size_t)KVDIM * S_LEN;
    half_t* wkh = wqh + (size_t)HDIM * HDIM;
    half_t* wvh = wkh + (size_t)KVDIM * HDIM;
    half_t* woh = wvh + (size_t)KVDIM * HDIM;
    half_t* o   = hh; // alias: hh is dead once qkv_kernel completes

    cvt_kernel<<<4480, 256, 0, stream>>>(hidden, Wq, Wk, Wv, Wo, hh, wqh, wkh, wvh, woh);
    qkv_kernel<<<dim3(16, 36), 256, 0, stream>>>(hh, wqh, bq, wkh, bk, wvh, bv, q, k, vt);
    rope_kernel<<<16384, 256, 0, stream>>>(q, k, cosT, sinT);
    attn_kernel<<<dim3(32, NHEADS), 256, 0, stream>>>(q, k, vt, doc, o);
    oproj_kernel<<<dim3(16, 28), 256, 0, stream>>>(o, woh, out);
}